// Round 6
// baseline (775.237 us; speedup 1.0000x reference)
//
#include <hip/hip_runtime.h>
#include <hip/hip_bf16.h>

// QuantizedLinear: out[8192,11008] = x[8192,4096] @ dequant(W)^T
// Round 6: R5's proven 4-phase schedule, inner shape switched to
// mfma_f32_32x32x16_bf16 (faster matrix pipe: 2495 vs 2075 TF ubench).
// Register choreography identical: a_=rb-pair (8 regs), b0_/b1_=4 regs each.

#define IN_F   4096
#define OUT_F  11008
#define M_DIM  8192
#define NGROUP 32

typedef __bf16 bf16x8 __attribute__((ext_vector_type(8)));
typedef float  f32x16 __attribute__((ext_vector_type(16)));
typedef unsigned short u16;
typedef u16 u16x8v __attribute__((ext_vector_type(8)));

__device__ __forceinline__ u16 f2bf(float f) {
  union { float f; unsigned u; } v; v.f = f;
  unsigned u = v.u;
  return (u16)((u + 0x7fffu + ((u >> 16) & 1u)) >> 16);  // RNE
}

__device__ __forceinline__ void gload_lds16(const void* gsrc, void* ldst) {
  __builtin_amdgcn_global_load_lds(
      (const __attribute__((address_space(1))) void*)gsrc,
      (__attribute__((address_space(3))) void*)ldst, 16, 0, 0);
}

// ---------------- dequant: packed 4-bit -> bf16 W[out][in] -----------------
__global__ __launch_bounds__(256) void dequant_w(const int* __restrict__ qw,
                                                 const int* __restrict__ qz,
                                                 const float* __restrict__ sc,
                                                 u16* __restrict__ W) {
  const int total = (IN_F / 2) * OUT_F / 4;  // int4 chunks
  int stride = gridDim.x * blockDim.x;
  for (int idx = blockIdx.x * blockDim.x + threadIdx.x; idx < total; idx += stride) {
    int j = idx << 2;
    int o = j >> 11;
    int g = (j >> 6) & 31;
    float z = (float)qz[(o << 5) + g];
    float s = sc[(o << 5) + g];
    int4 q = ((const int4*)qw)[idx];
    int qs0 = q.x, qs1 = q.y, qs2 = q.z, qs3 = q.w;
    u16x8v w;
    w[0] = f2bf(((float)(qs0 & 15) - z) * s);
    w[1] = f2bf(((float)((qs0 >> 4) & 15) - z) * s);
    w[2] = f2bf(((float)(qs1 & 15) - z) * s);
    w[3] = f2bf(((float)((qs1 >> 4) & 15) - z) * s);
    w[4] = f2bf(((float)(qs2 & 15) - z) * s);
    w[5] = f2bf(((float)((qs2 >> 4) & 15) - z) * s);
    w[6] = f2bf(((float)(qs3 & 15) - z) * s);
    w[7] = f2bf(((float)((qs3 >> 4) & 15) - z) * s);
    ((u16x8v*)W)[idx] = w;
  }
}

// ---------------- x fp32 -> bf16 -------------------------------------------
__global__ __launch_bounds__(256) void cvt_x(const float* __restrict__ x,
                                             u16* __restrict__ Xb) {
  const int total = M_DIM * IN_F / 8;
  int stride = gridDim.x * blockDim.x;
  for (int idx = blockIdx.x * blockDim.x + threadIdx.x; idx < total; idx += stride) {
    float4 a = ((const float4*)x)[idx * 2];
    float4 b = ((const float4*)x)[idx * 2 + 1];
    u16x8v v;
    v[0] = f2bf(a.x); v[1] = f2bf(a.y); v[2] = f2bf(a.z); v[3] = f2bf(a.w);
    v[4] = f2bf(b.x); v[5] = f2bf(b.y); v[6] = f2bf(b.z); v[7] = f2bf(b.w);
    ((u16x8v*)Xb)[idx] = v;
  }
}

// ---------------- 256x256 bf16 GEMM (32x32x16 MFMA): C = A * B^T -----------
// 8 waves 2Mx4N; wave tile 128x64 = 4 rb(32) x 2 cb(32).
// A-half mh = rows [mh*128): wave rows wr*64 + rbl*32, rbl 0..1 per half.
// B-half nh: wave cols wc*32 within half. Phases (R5 schedule, unchanged):
//  P0: rbh0 x cb0 | stage A1(u+1)->c^1      P1: rbh0 x cb1 | stage A0(u+2)->c
//  P2: rbh1 x cb0 | stage B0(u+2)->c, vmcnt(4)
//  P3: rbh1 x cb1 | stage B1(u+2)->c, prefetch next-tile frags

#define BAR       __builtin_amdgcn_s_barrier()
#define SCHED0    __builtin_amdgcn_sched_barrier(0)
#define LGKM0     asm volatile("s_waitcnt lgkmcnt(0)" ::: "memory")
#define VMCNT4    asm volatile("s_waitcnt vmcnt(4)" ::: "memory")
#define VMCNT6    asm volatile("s_waitcnt vmcnt(6)" ::: "memory")
#define PRIO(p)   __builtin_amdgcn_s_setprio(p)

__global__ __launch_bounds__(512, 2) void gemm256(const u16* __restrict__ A,
                                                  const u16* __restrict__ B,
                                                  float* __restrict__ C) {
  constexpr int K = IN_F, N = OUT_F;
  constexpr int NT = K / 64;  // 64 K-tiles
  __shared__ __align__(16) u16 sA[2][256 * 64];
  __shared__ __align__(16) u16 sB[2][256 * 64];

  const int NTN = OUT_F / 256;           // 43
  const int NWG = (M_DIM / 256) * NTN;   // 1376 (divisible by 8)
  int bid = blockIdx.x;
  int wg  = (bid & 7) * (NWG / 8) + (bid >> 3);  // bijective XCD swizzle
  int tm = wg / NTN, tn = wg - tm * NTN;
  int m0 = tm * 256, n0 = tn * 256;

  int tid  = threadIdx.x;
  int lane = tid & 63;
  int wave = tid >> 6;
  int wr = wave >> 2, wc = wave & 3;

  // staging: thread covers row (tid>>3), phys 16B slot tid&7.
  // phys slot s at row r holds global col-slot s^(r&7)  (involution).
  int rstage = tid >> 3;                               // 0..63
  int gslot  = ((tid & 7) ^ (rstage & 7)) << 3;        // global col elem
  int ldsoff = rstage * 64 + ((tid & 7) << 3);         // linear LDS elem
  const u16* Ag = A + (size_t)(m0 + rstage) * K + gslot;
  const u16* Bg = B + (size_t)(n0 + rstage) * K + gslot;

#define STAGE_A(cb_, h, kt) do {                                  \
    const u16* _g = Ag + (size_t)(h) * 128 * K + (kt) * 64;       \
    u16* _l = sA[cb_] + (h) * 128 * 64 + ldsoff;                  \
    gload_lds16(_g, _l);                                          \
    gload_lds16(_g + (size_t)64 * K, _l + 64 * 64);               \
  } while (0)

#define STAGE_B(cb_, h, kt) do {                                  \
    const u16* _g = Bg + (size_t)(h) * 128 * K + (kt) * 64;       \
    u16* _l = sB[cb_] + (h) * 128 * 64 + ldsoff;                  \
    gload_lds16(_g, _l);                                          \
    gload_lds16(_g + (size_t)64 * K, _l + 64 * 64);               \
  } while (0)

  // 32x32x16 fragment: lane holds row (lane&31), k = ks*16 + (lane>>5)*8 + i.
  // 16B slot index = ks*2 + (lane>>5), swizzled ^ (lane&7) (rows === lane&7 mod 8).
  int q32 = lane >> 5;
  int l7  = lane & 7;
  int slk0 = (((0 * 2 + q32) ^ l7) << 3);
  int slk1 = (((1 * 2 + q32) ^ l7) << 3);
  int slk2 = (((2 * 2 + q32) ^ l7) << 3);
  int slk3 = (((3 * 2 + q32) ^ l7) << 3);
  int abase = (wr * 64 + (lane & 31)) * 64;      // within A-half (elems)
  int bbase = (wc * 32 + (lane & 31)) * 64;      // within B-half

  bf16x8 a_[8], b0_[4], b1_[4];
  f32x16 acc[4][2] = {};

  // a_[rbl*4+ks] = A-frag of row-block rbl (of the current half), k-slice ks
#define LDA32(cb_, mh) do {                                       \
    const u16* _p = sA[cb_] + abase + (mh) * 8192;                \
    a_[0] = *(const bf16x8*)(_p + slk0);                          \
    a_[1] = *(const bf16x8*)(_p + slk1);                          \
    a_[2] = *(const bf16x8*)(_p + slk2);                          \
    a_[3] = *(const bf16x8*)(_p + slk3);                          \
    a_[4] = *(const bf16x8*)(_p + 2048 + slk0);                   \
    a_[5] = *(const bf16x8*)(_p + 2048 + slk1);                   \
    a_[6] = *(const bf16x8*)(_p + 2048 + slk2);                   \
    a_[7] = *(const bf16x8*)(_p + 2048 + slk3);                   \
  } while (0)

#define LDB32(cb_, nh, dst) do {                                  \
    const u16* _p = sB[cb_] + bbase + (nh) * 8192;                \
    dst[0] = *(const bf16x8*)(_p + slk0);                         \
    dst[1] = *(const bf16x8*)(_p + slk1);                         \
    dst[2] = *(const bf16x8*)(_p + slk2);                         \
    dst[3] = *(const bf16x8*)(_p + slk3);                         \
  } while (0)

  // 8 MFMAs, ks-major (dep distance 2 between chain links)
#define QUAD32(rbh, cb_, bq) do {                                              \
    _Pragma("unroll") for (int ks = 0; ks < 4; ks++) {                         \
      acc[(rbh)*2+0][cb_] = __builtin_amdgcn_mfma_f32_32x32x16_bf16(           \
          a_[0*4+ks], bq[ks], acc[(rbh)*2+0][cb_], 0, 0, 0);                   \
      acc[(rbh)*2+1][cb_] = __builtin_amdgcn_mfma_f32_32x32x16_bf16(           \
          a_[1*4+ks], bq[ks], acc[(rbh)*2+1][cb_], 0, 0, 0);                   \
    }                                                                          \
  } while (0)

  // same, with rolling A-prefetch: after the ks-pair consumes a_[*4+ks],
  // reload those two regs from `rp` (next phase's A source).
#define QUAD32_ROLLA(rbh, cb_, bq, rp) do {                                    \
    _Pragma("unroll") for (int ks = 0; ks < 4; ks++) {                         \
      acc[(rbh)*2+0][cb_] = __builtin_amdgcn_mfma_f32_32x32x16_bf16(           \
          a_[0*4+ks], bq[ks], acc[(rbh)*2+0][cb_], 0, 0, 0);                   \
      acc[(rbh)*2+1][cb_] = __builtin_amdgcn_mfma_f32_32x32x16_bf16(           \
          a_[1*4+ks], bq[ks], acc[(rbh)*2+1][cb_], 0, 0, 0);                   \
      int _s = (ks == 0) ? slk0 : (ks == 1) ? slk1 : (ks == 2) ? slk2 : slk3;  \
      a_[0*4+ks] = *(const bf16x8*)((rp) + _s);                                \
      a_[1*4+ks] = *(const bf16x8*)((rp) + 2048 + _s);                         \
    }                                                                          \
  } while (0)

#define TILE(c, u) do {                                           \
    int _k1 = ((u) + 1) & (NT - 1), _k2 = ((u) + 2) & (NT - 1);   \
    /* P0: rbh0 x cb0 */                                          \
    STAGE_A((c) ^ 1, 1, _k1);                                     \
    BAR; LGKM0; PRIO(1);                                          \
    LDB32(c, 1, b1_);                                             \
    QUAD32(0, 0, b0_);                                            \
    PRIO(0); BAR;                                                 \
    /* P1: rbh0 x cb1; roll a_ <- A-half1(c) */                   \
    STAGE_A(c, 0, _k2);                                           \
    BAR; LGKM0; PRIO(1);                                          \
    QUAD32_ROLLA(0, 1, b1_, sA[c] + abase + 8192);                \
    PRIO(0); BAR;                                                 \
    /* P2: rbh1 x cb0 */                                          \
    STAGE_B(c, 0, _k2);                                           \
    BAR; LGKM0; PRIO(1);                                          \
    QUAD32(1, 0, b0_);                                            \
    PRIO(0); VMCNT4; BAR;                                         \
    /* P3: rbh1 x cb1; prefetch b0_<-B0(c^1), roll a_<-A0(c^1) */ \
    STAGE_B(c, 1, _k2);                                           \
    BAR; LGKM0; PRIO(1);                                          \
    LDB32((c) ^ 1, 0, b0_);                                       \
    QUAD32_ROLLA(1, 1, b1_, sA[(c) ^ 1] + abase);                 \
    PRIO(0); BAR;                                                 \
  } while (0)

  // prologue: full tile0 + {A0,B0,B1} of tile1 staged; own-wave drain, then
  // barrier (others' rows visible), THEN preload frags (pinned below barrier).
  STAGE_A(0, 0, 0); STAGE_A(0, 1, 0);
  STAGE_B(0, 0, 0); STAGE_B(0, 1, 0);
  STAGE_A(1, 0, 1); STAGE_B(1, 0, 1); STAGE_B(1, 1, 1);
  VMCNT6; BAR;
  SCHED0;
  asm volatile("" ::: "memory");
  LDA32(0, 0);
  LDB32(0, 0, b0_);

#pragma unroll 1
  for (int u = 0; u < NT; u += 2) {
    TILE(0, u);
    TILE(1, u + 1);
  }

  // C/D (32x32, m74/m101): col = lane&31, row = (reg&3) + 8*(reg>>2) + 4*(lane>>5)
  // global row = (rb>>1)*128 + wr*64 + (rb&1)*32 + frag_row
  // global col = cb*128 + wc*32 + frag_col
  float* Cbase = C + (size_t)(m0 + wr * 64 + ((lane >> 5) << 2)) * N
                   + n0 + wc * 32 + (lane & 31);
#pragma unroll
  for (int rb = 0; rb < 4; rb++) {
    size_t ro = (size_t)((rb >> 1) * 128 + (rb & 1) * 32);
#pragma unroll
    for (int cb = 0; cb < 2; cb++) {
      int co = cb * 128;
#pragma unroll
      for (int reg = 0; reg < 16; reg++) {
        int r = (reg & 3) + 8 * (reg >> 2);
        Cbase[(ro + r) * N + co] = acc[rb][cb][reg];
      }
    }
  }
}

// ---------------- exact fp32 fallback (only if ws too small) ---------------
__global__ __launch_bounds__(256) void naive_gemm(const float* __restrict__ x,
                                                  const int* __restrict__ qw,
                                                  const int* __restrict__ qz,
                                                  const float* __restrict__ sc,
                                                  float* __restrict__ out) {
  __shared__ float xs[IN_F];
  int m = blockIdx.y;
  int n = blockIdx.x * 256 + threadIdx.x;
  for (int i = threadIdx.x; i < IN_F; i += 256) xs[i] = x[(size_t)m * IN_F + i];
  __syncthreads();
  float acc = 0.f;
  const int* qrow = qw + (size_t)n * (IN_F / 2);
  for (int g = 0; g < NGROUP; g++) {
    float z = (float)qz[n * NGROUP + g];
    float s = sc[n * NGROUP + g];
    for (int t = 0; t < 64; t++) {
      int q = qrow[g * 64 + t];
      acc += xs[g * 128 + 2 * t] * ((float)(q & 15) - z) * s;
      acc += xs[g * 128 + 2 * t + 1] * ((float)((q >> 4) & 15) - z) * s;
    }
  }
  out[(size_t)m * OUT_F + n] = acc;
}

extern "C" void kernel_launch(void* const* d_in, const int* in_sizes, int n_in,
                              void* d_out, int out_size, void* d_ws, size_t ws_size,
                              hipStream_t stream) {
  const float* x  = (const float*)d_in[0];
  const int*   qw = (const int*)d_in[1];
  const int*   qz = (const int*)d_in[2];
  const float* sc = (const float*)d_in[3];
  float* out = (float*)d_out;

  const size_t WBYTES = (size_t)OUT_F * IN_F * 2;
  const size_t XBYTES = (size_t)M_DIM * IN_F * 2;

  if (ws_size >= WBYTES + XBYTES) {
    u16* Wb = (u16*)d_ws;
    u16* Xb = (u16*)((char*)d_ws + WBYTES);
    dequant_w<<<2048, 256, 0, stream>>>(qw, qz, sc, Wb);
    cvt_x<<<2048, 256, 0, stream>>>(x, Xb);
    gemm256<<<(M_DIM / 256) * (OUT_F / 256), 512, 0, stream>>>(Xb, Wb, out);
  } else {
    naive_gemm<<<dim3(OUT_F / 256, M_DIM), 256, 0, stream>>>(x, qw, qz, sc, out);
  }
}

// Round 7
// 709.499 us; speedup vs baseline: 1.0927x; 1.0927x over previous
//
#include <hip/hip_runtime.h>
#include <hip/hip_bf16.h>

// QuantizedLinear: out[8192,11008] = x[8192,4096] @ dequant(W)^T
// Round 7: back to 16x16x32 fragments (0-conflict swizzle, R5-proven), but
// 2 phases per K-tile instead of 4 => 2 barriers/tile (was 8). All staging
// issued at phase start; A-rolls + B-reloads interleaved into 32-MFMA bursts;
// closing sequence per phase: vmcnt(4); lgkmcnt(0); s_barrier.

#define IN_F   4096
#define OUT_F  11008
#define M_DIM  8192
#define NGROUP 32

typedef __bf16 bf16x8 __attribute__((ext_vector_type(8)));
typedef float  f32x4  __attribute__((ext_vector_type(4)));
typedef unsigned short u16;
typedef u16 u16x8v __attribute__((ext_vector_type(8)));

__device__ __forceinline__ u16 f2bf(float f) {
  union { float f; unsigned u; } v; v.f = f;
  unsigned u = v.u;
  return (u16)((u + 0x7fffu + ((u >> 16) & 1u)) >> 16);  // RNE
}

__device__ __forceinline__ void gload_lds16(const void* gsrc, void* ldst) {
  __builtin_amdgcn_global_load_lds(
      (const __attribute__((address_space(1))) void*)gsrc,
      (__attribute__((address_space(3))) void*)ldst, 16, 0, 0);
}

// ---------------- dequant: packed 4-bit -> bf16 W[out][in] -----------------
__global__ __launch_bounds__(256) void dequant_w(const int* __restrict__ qw,
                                                 const int* __restrict__ qz,
                                                 const float* __restrict__ sc,
                                                 u16* __restrict__ W) {
  const int total = (IN_F / 2) * OUT_F / 4;  // int4 chunks
  int stride = gridDim.x * blockDim.x;
  for (int idx = blockIdx.x * blockDim.x + threadIdx.x; idx < total; idx += stride) {
    int j = idx << 2;
    int o = j >> 11;
    int g = (j >> 6) & 31;
    float z = (float)qz[(o << 5) + g];
    float s = sc[(o << 5) + g];
    int4 q = ((const int4*)qw)[idx];
    int qs0 = q.x, qs1 = q.y, qs2 = q.z, qs3 = q.w;
    u16x8v w;
    w[0] = f2bf(((float)(qs0 & 15) - z) * s);
    w[1] = f2bf(((float)((qs0 >> 4) & 15) - z) * s);
    w[2] = f2bf(((float)(qs1 & 15) - z) * s);
    w[3] = f2bf(((float)((qs1 >> 4) & 15) - z) * s);
    w[4] = f2bf(((float)(qs2 & 15) - z) * s);
    w[5] = f2bf(((float)((qs2 >> 4) & 15) - z) * s);
    w[6] = f2bf(((float)(qs3 & 15) - z) * s);
    w[7] = f2bf(((float)((qs3 >> 4) & 15) - z) * s);
    ((u16x8v*)W)[idx] = w;
  }
}

// ---------------- x fp32 -> bf16 -------------------------------------------
__global__ __launch_bounds__(256) void cvt_x(const float* __restrict__ x,
                                             u16* __restrict__ Xb) {
  const int total = M_DIM * IN_F / 8;
  int stride = gridDim.x * blockDim.x;
  for (int idx = blockIdx.x * blockDim.x + threadIdx.x; idx < total; idx += stride) {
    float4 a = ((const float4*)x)[idx * 2];
    float4 b = ((const float4*)x)[idx * 2 + 1];
    u16x8v v;
    v[0] = f2bf(a.x); v[1] = f2bf(a.y); v[2] = f2bf(a.z); v[3] = f2bf(a.w);
    v[4] = f2bf(b.x); v[5] = f2bf(b.y); v[6] = f2bf(b.z); v[7] = f2bf(b.w);
    ((u16x8v*)Xb)[idx] = v;
  }
}

// ---------------- 256x256 bf16 GEMM, 2 phases/K-tile: C = A * B^T ----------
// 8 waves 2Mx4N, wave tile 128x64 (4x4 frags of 16x16 per half-pair).
// A-half mh = rows [mh*128 + wr*64); B-half nh = cols [nh*128 + wc*32).
// PhA(u): quadrants (0,0),(0,1); stage A1(u+1)->c^1, A0(u+2)->c; roll a_<-A1(u).
// PhB(u): quadrants (1,0),(1,1); stage B0,B1(u+2)->c; reload b0_,b1_<-B(u+1),
//         roll a_<-A0(u+1). Close each phase: VMCNT4; LGKM0; BAR.
// vmcnt(4): PhA close drains prev-PhB's B-stages (B(u+1) landed for PhB's
// reloads); PhB close drains PhA's A-stages (A1(u+1),A0(u+2) landed).
// Cross-wave safety: every ds_read is drained by its wave's closing LGKM0
// before the barrier that precedes any overwriting stage; every stage is
// vmcnt-drained by its wave before the barrier that precedes any reader.

#define BAR       __builtin_amdgcn_s_barrier()
#define SCHED0    __builtin_amdgcn_sched_barrier(0)
#define LGKM0     asm volatile("s_waitcnt lgkmcnt(0)" ::: "memory")
#define VMCNT0    asm volatile("s_waitcnt vmcnt(0)" ::: "memory")
#define VMCNT4    asm volatile("s_waitcnt vmcnt(4)" ::: "memory")
#define PRIO(p)   __builtin_amdgcn_s_setprio(p)

__global__ __launch_bounds__(512, 2) void gemm256(const u16* __restrict__ A,
                                                  const u16* __restrict__ B,
                                                  float* __restrict__ C) {
  constexpr int K = IN_F, N = OUT_F;
  constexpr int NT = K / 64;  // 64 K-tiles
  __shared__ __align__(16) u16 sA[2][256 * 64];
  __shared__ __align__(16) u16 sB[2][256 * 64];

  const int NTN = OUT_F / 256;           // 43
  const int NWG = (M_DIM / 256) * NTN;   // 1376 (divisible by 8)
  int bid = blockIdx.x;
  int wg  = (bid & 7) * (NWG / 8) + (bid >> 3);  // bijective XCD swizzle
  int tm = wg / NTN, tn = wg - tm * NTN;
  int m0 = tm * 256, n0 = tn * 256;

  int tid  = threadIdx.x;
  int lane = tid & 63;
  int wave = tid >> 6;
  int wr = wave >> 2, wc = wave & 3;

  // staging: thread covers row (tid>>3), phys 16B slot tid&7.
  // phys slot s at row r holds global col-slot s^(r&7)  (involution).
  int rstage = tid >> 3;                               // 0..63
  int gslot  = ((tid & 7) ^ (rstage & 7)) << 3;        // global col elem
  int ldsoff = rstage * 64 + ((tid & 7) << 3);         // linear LDS elem
  const u16* Ag = A + (size_t)(m0 + rstage) * K + gslot;
  const u16* Bg = B + (size_t)(n0 + rstage) * K + gslot;

#define STAGE_A(cb, h, kt) do {                                   \
    const u16* _g = Ag + (size_t)(h) * 128 * K + (kt) * 64;       \
    u16* _l = sA[cb] + (h) * 128 * 64 + ldsoff;                   \
    gload_lds16(_g, _l);                                          \
    gload_lds16(_g + (size_t)64 * K, _l + 64 * 64);               \
  } while (0)

#define STAGE_B(cb, h, kt) do {                                   \
    const u16* _g = Bg + (size_t)(h) * 128 * K + (kt) * 64;       \
    u16* _l = sB[cb] + (h) * 128 * 64 + ldsoff;                   \
    gload_lds16(_g, _l);                                          \
    gload_lds16(_g + (size_t)64 * K, _l + 64 * 64);               \
  } while (0)

  // fragment reads: lane reads row base+(lane&15), k-quad q=lane>>4, slice ks.
  // phys 16B slot = (ks*4+q) ^ (lane&7)   (row&7 == lane&7: all row bases %8==0)
  int q8  = lane >> 4;
  int sl0 = ((q8 ^ (lane & 7)) << 3);            // ks=0, elems
  int sl1 = (((q8 | 4) ^ (lane & 7)) << 3);      // ks=1
  int abase = (wr * 64 + (lane & 15)) * 64;      // within A-half
  int bbase = (wc * 32 + (lane & 15)) * 64;      // within B-half

  bf16x8 a_[8], b0_[4], b1_[4];
  f32x4 acc[8][4] = {};

#define LDA(cb, mh) do {                                          \
    const u16* _p = sA[cb] + abase + (mh) * 8192;                 \
    a_[0] = *(const bf16x8*)(_p + sl0);                           \
    a_[1] = *(const bf16x8*)(_p + sl1);                           \
    a_[2] = *(const bf16x8*)(_p + 1024 + sl0);                    \
    a_[3] = *(const bf16x8*)(_p + 1024 + sl1);                    \
    a_[4] = *(const bf16x8*)(_p + 2048 + sl0);                    \
    a_[5] = *(const bf16x8*)(_p + 2048 + sl1);                    \
    a_[6] = *(const bf16x8*)(_p + 3072 + sl0);                    \
    a_[7] = *(const bf16x8*)(_p + 3072 + sl1);                    \
  } while (0)

#define LDB(cb, nh, dst) do {                                     \
    const u16* _p = sB[cb] + bbase + (nh) * 8192;                 \
    dst[0] = *(const bf16x8*)(_p + sl0);                          \
    dst[1] = *(const bf16x8*)(_p + sl1);                          \
    dst[2] = *(const bf16x8*)(_p + 1024 + sl0);                   \
    dst[3] = *(const bf16x8*)(_p + 1024 + sl1);                   \
  } while (0)

#define QUAD(mh, nh, bq) do {                                                  \
    _Pragma("unroll") for (int mf = 0; mf < 4; mf++)                           \
      _Pragma("unroll") for (int nf = 0; nf < 2; nf++) {                       \
        acc[(mh)*4+mf][(nh)*2+nf] = __builtin_amdgcn_mfma_f32_16x16x32_bf16(   \
            a_[mf*2+0], bq[nf*2+0], acc[(mh)*4+mf][(nh)*2+nf], 0, 0, 0);       \
        acc[(mh)*4+mf][(nh)*2+nf] = __builtin_amdgcn_mfma_f32_16x16x32_bf16(   \
            a_[mf*2+1], bq[nf*2+1], acc[(mh)*4+mf][(nh)*2+nf], 0, 0, 0);       \
      }                                                                        \
  } while (0)

  // QUAD with pairwise rolling A-prefetch: after each mf-block (a_[2mf..2mf+1]
  // dead for the rest of the phase), reload them from `rp` for the NEXT phase.
#define QUAD_ROLLA(mh, nh, bq, rp) do {                                        \
    _Pragma("unroll") for (int mf = 0; mf < 4; mf++) {                         \
      _Pragma("unroll") for (int nf = 0; nf < 2; nf++) {                       \
        acc[(mh)*4+mf][(nh)*2+nf] = __builtin_amdgcn_mfma_f32_16x16x32_bf16(   \
            a_[mf*2+0], bq[nf*2+0], acc[(mh)*4+mf][(nh)*2+nf], 0, 0, 0);       \
        acc[(mh)*4+mf][(nh)*2+nf] = __builtin_amdgcn_mfma_f32_16x16x32_bf16(   \
            a_[mf*2+1], bq[nf*2+1], acc[(mh)*4+mf][(nh)*2+nf], 0, 0, 0);       \
      }                                                                        \
      a_[mf*2+0] = *(const bf16x8*)((rp) + mf * 1024 + sl0);                   \
      a_[mf*2+1] = *(const bf16x8*)((rp) + mf * 1024 + sl1);                   \
    }                                                                          \
  } while (0)

  // Two phases per K-tile (buf c = u&1):
#define TILE2(c, u) do {                                          \
    int _k1 = ((u) + 1) & (NT - 1), _k2 = ((u) + 2) & (NT - 1);   \
    /* PhA: (0,0),(0,1) with a_=A0(u); stage A1(u+1)->c^1 and     \
       A0(u+2)->c (region's readers drained at u-1.PhB close);    \
       roll a_<-A1(u) during second quadrant. */                  \
    STAGE_A((c) ^ 1, 1, _k1);                                     \
    STAGE_A(c, 0, _k2);                                           \
    PRIO(1);                                                      \
    QUAD(0, 0, b0_);                                              \
    QUAD_ROLLA(0, 1, b1_, sA[c] + abase + 8192);                  \
    PRIO(0); VMCNT4; LGKM0; BAR;                                  \
    /* PhB: (1,0),(1,1) with a_=A1(u); stage B0,B1(u+2)->c;       \
       reload b0_,b1_<-B(u+1) (landed: PhA's vmcnt drained        \
       u-1.PhB's B-stages); roll a_<-A0(u+1). */                  \
    STAGE_B(c, 0, _k2);                                           \
    STAGE_B(c, 1, _k2);                                           \
    PRIO(1);                                                      \
    QUAD(1, 0, b0_);                                              \
    LDB((c) ^ 1, 0, b0_);                                         \
    QUAD_ROLLA(1, 1, b1_, sA[(c) ^ 1] + abase);                   \
    LDB((c) ^ 1, 1, b1_);                                         \
    PRIO(0); VMCNT4; LGKM0; BAR;                                  \
  } while (0)

  // prologue: stage tile0 (A0,A1,B0,B1) + A0(1); drain ALL (vmcnt 0), barrier
  // (every wave's rows visible), then preload frags; finally stage B(1) so
  // exactly 4 loads are in flight entering the loop (steady-state invariant).
  STAGE_A(0, 0, 0); STAGE_A(0, 1, 0);
  STAGE_B(0, 0, 0); STAGE_B(0, 1, 0);
  STAGE_A(1, 0, 1);
  VMCNT0; BAR;
  SCHED0;
  asm volatile("" ::: "memory");
  LDA(0, 0);
  LDB(0, 0, b0_);
  LDB(0, 1, b1_);
  STAGE_B(1, 0, 1); STAGE_B(1, 1, 1);

#pragma unroll 1
  for (int u = 0; u < NT; u += 2) {
    TILE2(0, u);
    TILE2(1, u + 1);
  }

  // C/D layout: col = lane&15, row = (lane>>4)*4 + j
  // output row = (m>>2)*128 + wr*64 + (m&3)*16 + (lane>>4)*4 + j
  // output col = (n>>1)*128 + wc*32 + (n&1)*16 + (lane&15)
  float* Cp = C + (size_t)(m0 + wr * 64 + ((lane >> 4) << 2)) * N
                + n0 + wc * 32 + (lane & 15);
#pragma unroll
  for (int m = 0; m < 8; m++) {
    int roff = (m >> 2) * 128 + (m & 3) * 16;
#pragma unroll
    for (int n = 0; n < 4; n++) {
      int coff = (n >> 1) * 128 + (n & 1) * 16;
#pragma unroll
      for (int j = 0; j < 4; j++)
        Cp[(size_t)(roff + j) * N + coff] = acc[m][n][j];
    }
  }
}

// ---------------- exact fp32 fallback (only if ws too small) ---------------
__global__ __launch_bounds__(256) void naive_gemm(const float* __restrict__ x,
                                                  const int* __restrict__ qw,
                                                  const int* __restrict__ qz,
                                                  const float* __restrict__ sc,
                                                  float* __restrict__ out) {
  __shared__ float xs[IN_F];
  int m = blockIdx.y;
  int n = blockIdx.x * 256 + threadIdx.x;
  for (int i = threadIdx.x; i < IN_F; i += 256) xs[i] = x[(size_t)m * IN_F + i];
  __syncthreads();
  float acc = 0.f;
  const int* qrow = qw + (size_t)n * (IN_F / 2);
  for (int g = 0; g < NGROUP; g++) {
    float z = (float)qz[n * NGROUP + g];
    float s = sc[n * NGROUP + g];
    for (int t = 0; t < 64; t++) {
      int q = qrow[g * 64 + t];
      acc += xs[g * 128 + 2 * t] * ((float)(q & 15) - z) * s;
      acc += xs[g * 128 + 2 * t + 1] * ((float)((q >> 4) & 15) - z) * s;
    }
  }
  out[(size_t)m * OUT_F + n] = acc;
}

extern "C" void kernel_launch(void* const* d_in, const int* in_sizes, int n_in,
                              void* d_out, int out_size, void* d_ws, size_t ws_size,
                              hipStream_t stream) {
  const float* x  = (const float*)d_in[0];
  const int*   qw = (const int*)d_in[1];
  const int*   qz = (const int*)d_in[2];
  const float* sc = (const float*)d_in[3];
  float* out = (float*)d_out;

  const size_t WBYTES = (size_t)OUT_F * IN_F * 2;
  const size_t XBYTES = (size_t)M_DIM * IN_F * 2;

  if (ws_size >= WBYTES + XBYTES) {
    u16* Wb = (u16*)d_ws;
    u16* Xb = (u16*)((char*)d_ws + WBYTES);
    dequant_w<<<2048, 256, 0, stream>>>(qw, qz, sc, Wb);
    cvt_x<<<2048, 256, 0, stream>>>(x, Xb);
    gemm256<<<(M_DIM / 256) * (OUT_F / 256), 512, 0, stream>>>(Xb, Wb, out);
  } else {
    naive_gemm<<<dim3(OUT_F / 256, M_DIM), 256, 0, stream>>>(x, qw, qz, sc, out);
  }
}

// Round 8
// 704.859 us; speedup vs baseline: 1.0998x; 1.0066x over previous
//
#include <hip/hip_runtime.h>
#include <hip/hip_bf16.h>

// QuantizedLinear: out[8192,11008] = x[8192,4096] @ dequant(W)^T
// Round 8: R7 structure, single change: MFMA ordering ks-OUTER so same-acc
// MFMAs are 8 apart (was back-to-back, dep distance 1 -> pipe stall).

#define IN_F   4096
#define OUT_F  11008
#define M_DIM  8192
#define NGROUP 32

typedef __bf16 bf16x8 __attribute__((ext_vector_type(8)));
typedef float  f32x4  __attribute__((ext_vector_type(4)));
typedef unsigned short u16;
typedef u16 u16x8v __attribute__((ext_vector_type(8)));

__device__ __forceinline__ u16 f2bf(float f) {
  union { float f; unsigned u; } v; v.f = f;
  unsigned u = v.u;
  return (u16)((u + 0x7fffu + ((u >> 16) & 1u)) >> 16);  // RNE
}

__device__ __forceinline__ void gload_lds16(const void* gsrc, void* ldst) {
  __builtin_amdgcn_global_load_lds(
      (const __attribute__((address_space(1))) void*)gsrc,
      (__attribute__((address_space(3))) void*)ldst, 16, 0, 0);
}

// ---------------- dequant: packed 4-bit -> bf16 W[out][in] -----------------
__global__ __launch_bounds__(256) void dequant_w(const int* __restrict__ qw,
                                                 const int* __restrict__ qz,
                                                 const float* __restrict__ sc,
                                                 u16* __restrict__ W) {
  const int total = (IN_F / 2) * OUT_F / 4;  // int4 chunks
  int stride = gridDim.x * blockDim.x;
  for (int idx = blockIdx.x * blockDim.x + threadIdx.x; idx < total; idx += stride) {
    int j = idx << 2;
    int o = j >> 11;
    int g = (j >> 6) & 31;
    float z = (float)qz[(o << 5) + g];
    float s = sc[(o << 5) + g];
    int4 q = ((const int4*)qw)[idx];
    int qs0 = q.x, qs1 = q.y, qs2 = q.z, qs3 = q.w;
    u16x8v w;
    w[0] = f2bf(((float)(qs0 & 15) - z) * s);
    w[1] = f2bf(((float)((qs0 >> 4) & 15) - z) * s);
    w[2] = f2bf(((float)(qs1 & 15) - z) * s);
    w[3] = f2bf(((float)((qs1 >> 4) & 15) - z) * s);
    w[4] = f2bf(((float)(qs2 & 15) - z) * s);
    w[5] = f2bf(((float)((qs2 >> 4) & 15) - z) * s);
    w[6] = f2bf(((float)(qs3 & 15) - z) * s);
    w[7] = f2bf(((float)((qs3 >> 4) & 15) - z) * s);
    ((u16x8v*)W)[idx] = w;
  }
}

// ---------------- x fp32 -> bf16 -------------------------------------------
__global__ __launch_bounds__(256) void cvt_x(const float* __restrict__ x,
                                             u16* __restrict__ Xb) {
  const int total = M_DIM * IN_F / 8;
  int stride = gridDim.x * blockDim.x;
  for (int idx = blockIdx.x * blockDim.x + threadIdx.x; idx < total; idx += stride) {
    float4 a = ((const float4*)x)[idx * 2];
    float4 b = ((const float4*)x)[idx * 2 + 1];
    u16x8v v;
    v[0] = f2bf(a.x); v[1] = f2bf(a.y); v[2] = f2bf(a.z); v[3] = f2bf(a.w);
    v[4] = f2bf(b.x); v[5] = f2bf(b.y); v[6] = f2bf(b.z); v[7] = f2bf(b.w);
    ((u16x8v*)Xb)[idx] = v;
  }
}

// ---------------- 256x256 bf16 GEMM, 2 phases/K-tile: C = A * B^T ----------
// 8 waves 2Mx4N, wave tile 128x64. A-half mh = rows [mh*128 + wr*64);
// B-half nh = cols [nh*128 + wc*32).
// PhA(u): quadrants (0,0),(0,1); stage A1(u+1)->c^1, A0(u+2)->c; roll a_<-A1(u).
// PhB(u): quadrants (1,0),(1,1); stage B0,B1(u+2)->c; reload b0_,b1_<-B(u+1),
//         roll a_<-A0(u+1). Close each phase: VMCNT4; LGKM0; BAR.

#define BAR       __builtin_amdgcn_s_barrier()
#define SCHED0    __builtin_amdgcn_sched_barrier(0)
#define LGKM0     asm volatile("s_waitcnt lgkmcnt(0)" ::: "memory")
#define VMCNT0    asm volatile("s_waitcnt vmcnt(0)" ::: "memory")
#define VMCNT4    asm volatile("s_waitcnt vmcnt(4)" ::: "memory")
#define PRIO(p)   __builtin_amdgcn_s_setprio(p)

__global__ __launch_bounds__(512, 2) void gemm256(const u16* __restrict__ A,
                                                  const u16* __restrict__ B,
                                                  float* __restrict__ C) {
  constexpr int K = IN_F, N = OUT_F;
  constexpr int NT = K / 64;  // 64 K-tiles
  __shared__ __align__(16) u16 sA[2][256 * 64];
  __shared__ __align__(16) u16 sB[2][256 * 64];

  const int NTN = OUT_F / 256;           // 43
  const int NWG = (M_DIM / 256) * NTN;   // 1376 (divisible by 8)
  int bid = blockIdx.x;
  int wg  = (bid & 7) * (NWG / 8) + (bid >> 3);  // bijective XCD swizzle
  int tm = wg / NTN, tn = wg - tm * NTN;
  int m0 = tm * 256, n0 = tn * 256;

  int tid  = threadIdx.x;
  int lane = tid & 63;
  int wave = tid >> 6;
  int wr = wave >> 2, wc = wave & 3;

  // staging: thread covers row (tid>>3), phys 16B slot tid&7.
  // phys slot s at row r holds global col-slot s^(r&7)  (involution).
  int rstage = tid >> 3;                               // 0..63
  int gslot  = ((tid & 7) ^ (rstage & 7)) << 3;        // global col elem
  int ldsoff = rstage * 64 + ((tid & 7) << 3);         // linear LDS elem
  const u16* Ag = A + (size_t)(m0 + rstage) * K + gslot;
  const u16* Bg = B + (size_t)(n0 + rstage) * K + gslot;

#define STAGE_A(cb, h, kt) do {                                   \
    const u16* _g = Ag + (size_t)(h) * 128 * K + (kt) * 64;       \
    u16* _l = sA[cb] + (h) * 128 * 64 + ldsoff;                   \
    gload_lds16(_g, _l);                                          \
    gload_lds16(_g + (size_t)64 * K, _l + 64 * 64);               \
  } while (0)

#define STAGE_B(cb, h, kt) do {                                   \
    const u16* _g = Bg + (size_t)(h) * 128 * K + (kt) * 64;       \
    u16* _l = sB[cb] + (h) * 128 * 64 + ldsoff;                   \
    gload_lds16(_g, _l);                                          \
    gload_lds16(_g + (size_t)64 * K, _l + 64 * 64);               \
  } while (0)

  // fragment reads: lane reads row base+(lane&15), k-quad q=lane>>4, slice ks.
  // phys 16B slot = (ks*4+q) ^ (lane&7)   (row&7 == lane&7: all row bases %8==0)
  int q8  = lane >> 4;
  int sl0 = ((q8 ^ (lane & 7)) << 3);            // ks=0, elems
  int sl1 = (((q8 | 4) ^ (lane & 7)) << 3);      // ks=1
  int abase = (wr * 64 + (lane & 15)) * 64;      // within A-half
  int bbase = (wc * 32 + (lane & 15)) * 64;      // within B-half

  bf16x8 a_[8], b0_[4], b1_[4];
  f32x4 acc[8][4] = {};

#define LDA(cb, mh) do {                                          \
    const u16* _p = sA[cb] + abase + (mh) * 8192;                 \
    a_[0] = *(const bf16x8*)(_p + sl0);                           \
    a_[1] = *(const bf16x8*)(_p + sl1);                           \
    a_[2] = *(const bf16x8*)(_p + 1024 + sl0);                    \
    a_[3] = *(const bf16x8*)(_p + 1024 + sl1);                    \
    a_[4] = *(const bf16x8*)(_p + 2048 + sl0);                    \
    a_[5] = *(const bf16x8*)(_p + 2048 + sl1);                    \
    a_[6] = *(const bf16x8*)(_p + 3072 + sl0);                    \
    a_[7] = *(const bf16x8*)(_p + 3072 + sl1);                    \
  } while (0)

#define LDB(cb, nh, dst) do {                                     \
    const u16* _p = sB[cb] + bbase + (nh) * 8192;                 \
    dst[0] = *(const bf16x8*)(_p + sl0);                          \
    dst[1] = *(const bf16x8*)(_p + sl1);                          \
    dst[2] = *(const bf16x8*)(_p + 1024 + sl0);                   \
    dst[3] = *(const bf16x8*)(_p + 1024 + sl1);                   \
  } while (0)

  // ks-OUTER MFMA ordering: all 8 ks=0 MFMAs (8 distinct accumulators), then
  // all 8 ks=1. Same-acc dep distance = 8 (was 1).
#define QUAD(mh, nh, bq) do {                                                  \
    _Pragma("unroll") for (int mf = 0; mf < 4; mf++)                           \
      _Pragma("unroll") for (int nf = 0; nf < 2; nf++)                         \
        acc[(mh)*4+mf][(nh)*2+nf] = __builtin_amdgcn_mfma_f32_16x16x32_bf16(   \
            a_[mf*2+0], bq[nf*2+0], acc[(mh)*4+mf][(nh)*2+nf], 0, 0, 0);       \
    _Pragma("unroll") for (int mf = 0; mf < 4; mf++)                           \
      _Pragma("unroll") for (int nf = 0; nf < 2; nf++)                         \
        acc[(mh)*4+mf][(nh)*2+nf] = __builtin_amdgcn_mfma_f32_16x16x32_bf16(   \
            a_[mf*2+1], bq[nf*2+1], acc[(mh)*4+mf][(nh)*2+nf], 0, 0, 0);       \
  } while (0)

  // same, with rolling A-prefetch folded into the ks=1 pass (a-pair fully
  // dead once its ks=1 MFMAs issued).
#define QUAD_ROLLA(mh, nh, bq, rp) do {                                        \
    _Pragma("unroll") for (int mf = 0; mf < 4; mf++)                           \
      _Pragma("unroll") for (int nf = 0; nf < 2; nf++)                         \
        acc[(mh)*4+mf][(nh)*2+nf] = __builtin_amdgcn_mfma_f32_16x16x32_bf16(   \
            a_[mf*2+0], bq[nf*2+0], acc[(mh)*4+mf][(nh)*2+nf], 0, 0, 0);       \
    _Pragma("unroll") for (int mf = 0; mf < 4; mf++) {                         \
      _Pragma("unroll") for (int nf = 0; nf < 2; nf++)                         \
        acc[(mh)*4+mf][(nh)*2+nf] = __builtin_amdgcn_mfma_f32_16x16x32_bf16(   \
            a_[mf*2+1], bq[nf*2+1], acc[(mh)*4+mf][(nh)*2+nf], 0, 0, 0);       \
      a_[mf*2+0] = *(const bf16x8*)((rp) + mf * 1024 + sl0);                   \
      a_[mf*2+1] = *(const bf16x8*)((rp) + mf * 1024 + sl1);                   \
    }                                                                          \
  } while (0)

  // Two phases per K-tile (buf c = u&1):
#define TILE2(c, u) do {                                          \
    int _k1 = ((u) + 1) & (NT - 1), _k2 = ((u) + 2) & (NT - 1);   \
    /* PhA: (0,0),(0,1) with a_=A0(u); stage A1(u+1)->c^1 and     \
       A0(u+2)->c; roll a_<-A1(u) during second quadrant. */      \
    STAGE_A((c) ^ 1, 1, _k1);                                     \
    STAGE_A(c, 0, _k2);                                           \
    PRIO(1);                                                      \
    QUAD(0, 0, b0_);                                              \
    QUAD_ROLLA(0, 1, b1_, sA[c] + abase + 8192);                  \
    PRIO(0); VMCNT4; LGKM0; BAR;                                  \
    /* PhB: (1,0),(1,1) with a_=A1(u); stage B0,B1(u+2)->c;       \
       reload b0_,b1_<-B(u+1); roll a_<-A0(u+1). */               \
    STAGE_B(c, 0, _k2);                                           \
    STAGE_B(c, 1, _k2);                                           \
    PRIO(1);                                                      \
    QUAD(1, 0, b0_);                                              \
    LDB((c) ^ 1, 0, b0_);                                         \
    QUAD_ROLLA(1, 1, b1_, sA[(c) ^ 1] + abase);                   \
    LDB((c) ^ 1, 1, b1_);                                         \
    PRIO(0); VMCNT4; LGKM0; BAR;                                  \
  } while (0)

  // prologue: stage tile0 (A0,A1,B0,B1) + A0(1); drain ALL (vmcnt 0), barrier
  // (every wave's rows visible), then preload frags; finally stage B(1) so
  // exactly 4 loads are in flight entering the loop (steady-state invariant).
  STAGE_A(0, 0, 0); STAGE_A(0, 1, 0);
  STAGE_B(0, 0, 0); STAGE_B(0, 1, 0);
  STAGE_A(1, 0, 1);
  VMCNT0; BAR;
  SCHED0;
  asm volatile("" ::: "memory");
  LDA(0, 0);
  LDB(0, 0, b0_);
  LDB(0, 1, b1_);
  STAGE_B(1, 0, 1); STAGE_B(1, 1, 1);

#pragma unroll 1
  for (int u = 0; u < NT; u += 2) {
    TILE2(0, u);
    TILE2(1, u + 1);
  }

  // C/D layout: col = lane&15, row = (lane>>4)*4 + j
  // output row = (m>>2)*128 + wr*64 + (m&3)*16 + (lane>>4)*4 + j
  // output col = (n>>1)*128 + wc*32 + (n&1)*16 + (lane&15)
  float* Cp = C + (size_t)(m0 + wr * 64 + ((lane >> 4) << 2)) * N
                + n0 + wc * 32 + (lane & 15);
#pragma unroll
  for (int m = 0; m < 8; m++) {
    int roff = (m >> 2) * 128 + (m & 3) * 16;
#pragma unroll
    for (int n = 0; n < 4; n++) {
      int coff = (n >> 1) * 128 + (n & 1) * 16;
#pragma unroll
      for (int j = 0; j < 4; j++)
        Cp[(size_t)(roff + j) * N + coff] = acc[m][n][j];
    }
  }
}

// ---------------- exact fp32 fallback (only if ws too small) ---------------
__global__ __launch_bounds__(256) void naive_gemm(const float* __restrict__ x,
                                                  const int* __restrict__ qw,
                                                  const int* __restrict__ qz,
                                                  const float* __restrict__ sc,
                                                  float* __restrict__ out) {
  __shared__ float xs[IN_F];
  int m = blockIdx.y;
  int n = blockIdx.x * 256 + threadIdx.x;
  for (int i = threadIdx.x; i < IN_F; i += 256) xs[i] = x[(size_t)m * IN_F + i];
  __syncthreads();
  float acc = 0.f;
  const int* qrow = qw + (size_t)n * (IN_F / 2);
  for (int g = 0; g < NGROUP; g++) {
    float z = (float)qz[n * NGROUP + g];
    float s = sc[n * NGROUP + g];
    for (int t = 0; t < 64; t++) {
      int q = qrow[g * 64 + t];
      acc += xs[g * 128 + 2 * t] * ((float)(q & 15) - z) * s;
      acc += xs[g * 128 + 2 * t + 1] * ((float)((q >> 4) & 15) - z) * s;
    }
  }
  out[(size_t)m * OUT_F + n] = acc;
}

extern "C" void kernel_launch(void* const* d_in, const int* in_sizes, int n_in,
                              void* d_out, int out_size, void* d_ws, size_t ws_size,
                              hipStream_t stream) {
  const float* x  = (const float*)d_in[0];
  const int*   qw = (const int*)d_in[1];
  const int*   qz = (const int*)d_in[2];
  const float* sc = (const float*)d_in[3];
  float* out = (float*)d_out;

  const size_t WBYTES = (size_t)OUT_F * IN_F * 2;
  const size_t XBYTES = (size_t)M_DIM * IN_F * 2;

  if (ws_size >= WBYTES + XBYTES) {
    u16* Wb = (u16*)d_ws;
    u16* Xb = (u16*)((char*)d_ws + WBYTES);
    dequant_w<<<2048, 256, 0, stream>>>(qw, qz, sc, Wb);
    cvt_x<<<2048, 256, 0, stream>>>(x, Xb);
    gemm256<<<(M_DIM / 256) * (OUT_F / 256), 512, 0, stream>>>(Xb, Wb, out);
  } else {
    naive_gemm<<<dim3(OUT_F / 256, M_DIM), 256, 0, stream>>>(x, qw, qz, sc, out);
  }
}